// Round 3
// baseline (182.913 us; speedup 1.0000x reference)
//
#include <hip/hip_runtime.h>
#include <hip/hip_bf16.h>

#define NDIM 2048
#define QDIM 1024
#define SDIM 512
#define NBINS 20

typedef __attribute__((ext_vector_type(8))) short bf16x8;
typedef __attribute__((ext_vector_type(4))) float f32x4;

__device__ __forceinline__ unsigned short f2bf(float f) {
  unsigned int u = __builtin_bit_cast(unsigned int, f);
  u += 0x7fffu + ((u >> 16) & 1u);   // round-to-nearest-even (no NaN in this data)
  return (unsigned short)(u >> 16);
}

// ---------------- K1: local calibration (4 rows/block) + rowsum + atomic colsum
__global__ __launch_bounds__(256) void k_calib(const float* __restrict__ graph,
                                               const float* __restrict__ calib_w,
                                               float* __restrict__ g0,
                                               float* __restrict__ rowsum,
                                               float* __restrict__ colsum) {
  __shared__ float sp[NBINS];
  __shared__ float red[256];
  int t = threadIdx.x;
  if (t == 0) {   // 20-bin softmax, recomputed per block (trivial)
    float m = -1e30f;
    for (int b = 0; b < NBINS; b++) m = fmaxf(m, calib_w[b]);
    float e[NBINS]; float s = 0.f;
    for (int b = 0; b < NBINS; b++) { e[b] = __expf(calib_w[b] - m); s += e[b]; }
    float inv = 1.0f / s;
    for (int b = 0; b < NBINS; b++) sp[b] = e[b] * inv;
  }
  __syncthreads();
  float p[NBINS];
  #pragma unroll
  for (int b = 0; b < NBINS; b++) p[b] = sp[b];
  int r0 = blockIdx.x * 4;
  float colacc[8] = {0.f,0.f,0.f,0.f,0.f,0.f,0.f,0.f};
  for (int r = 0; r < 4; r++) {
    int row = r0 + r;
    const float* grow = graph + (size_t)row * NDIM;
    float* orow = g0 + (size_t)row * NDIM;
    float rs = 0.f;
    #pragma unroll
    for (int c = 0; c < 8; c++) {
      int j = c * 256 + t;
      float g = grow[j];
      float v = 0.f;
      if (g > 0.f) {
        float num = 0.f, den = 0.f;
        #pragma unroll
        for (int b = 0; b < NBINS; b++) {
          float d = g - (float)b * (1.0f / 19.0f);
          float z = __expf(-950.0f * d * d);   // sig = (1/19)/50 = 1/950 for all bins
          den += z; num += z * p[b];
        }
        v = den > 0.f ? num / den : 0.f;
      }
      orow[j] = v;
      rs += v;
      colacc[c] += v;
    }
    red[t] = rs; __syncthreads();
    for (int st = 128; st > 0; st >>= 1) { if (t < st) red[t] += red[t+st]; __syncthreads(); }
    if (t == 0) rowsum[row] = red[0];
    __syncthreads();
  }
  #pragma unroll
  for (int c = 0; c < 8; c++) atomicAdd(&colsum[c * 256 + t], colacc[c]);
}

// ---------------- K2: factors (single block, 1024 threads): col_w softmax + scale vecs
__global__ __launch_bounds__(1024) void k_factors(const float* __restrict__ rowsum,
                                                  const float* __restrict__ colsum,
                                                  const float* __restrict__ col_w,
                                                  float* __restrict__ leftv,
                                                  float* __restrict__ rightc,
                                                  float* __restrict__ mvec) {
  __shared__ float red[1024];
  int t = threadIdx.x;
  float a = col_w[t], b = col_w[t + 1024];
  red[t] = fmaxf(a, b); __syncthreads();
  for (int st = 512; st > 0; st >>= 1) { if (t < st) red[t] = fmaxf(red[t], red[t+st]); __syncthreads(); }
  float gmax = red[0]; __syncthreads();
  float ea = __expf(a - gmax), eb = __expf(b - gmax);
  red[t] = ea + eb; __syncthreads();
  for (int st = 512; st > 0; st >>= 1) { if (t < st) red[t] += red[t+st]; __syncthreads(); }
  float scale = (float)NDIM / red[0];
  #pragma unroll
  for (int h = 0; h < 2; h++) {
    int j = t + h * 1024;
    float cwj = (h == 0 ? ea : eb) * scale;
    float rsum = rowsum[j], csum = colsum[j];
    float l = rsum > 0.f ? 1.0f / sqrtf(rsum) : 0.f;   // divide_no_nan(1, sqrt(.))
    float rr = csum > 0.f ? 1.0f / sqrtf(csum) : 0.f;
    float rc = rr * cwj;
    leftv[j] = l;
    rightc[j] = rc;
    mvec[j] = l * rc;
  }
}

// ---------------- K3: fused panel builders
// blocks [0,QDIM): Aq[q][k] = g0[qid[q]][k]*leftv   (bf16, coalesced)
// blocks [QDIM,QDIM+SDIM): Bt[s][k] = g0[k][sid[s]]*mvec[k]*rightc[sid[s]]
__global__ __launch_bounds__(256) void k_gather(const float* __restrict__ g0,
                                                const int* __restrict__ qid,
                                                const int* __restrict__ sid,
                                                const float* __restrict__ leftv,
                                                const float* __restrict__ rightc,
                                                const float* __restrict__ mvec,
                                                unsigned short* __restrict__ Aq,
                                                unsigned short* __restrict__ Bt) {
  int b = blockIdx.x, t = threadIdx.x;
  if (b < QDIM) {
    int row = qid[b];
    float lf = leftv[row];
    const float4* src = (const float4*)(g0 + (size_t)row * NDIM);
    float4 v0 = src[t * 2];
    float4 v1 = src[t * 2 + 1];
    unsigned short tmp[8];
    tmp[0] = f2bf(v0.x * lf); tmp[1] = f2bf(v0.y * lf);
    tmp[2] = f2bf(v0.z * lf); tmp[3] = f2bf(v0.w * lf);
    tmp[4] = f2bf(v1.x * lf); tmp[5] = f2bf(v1.y * lf);
    tmp[6] = f2bf(v1.z * lf); tmp[7] = f2bf(v1.w * lf);
    uint4 packed;
    __builtin_memcpy(&packed, tmp, 16);
    *(uint4*)(Aq + (size_t)b * NDIM + t * 8) = packed;
  } else {
    int s = b - QDIM;
    int col = sid[s];
    float rsc = rightc[col];
    unsigned short* dst = Bt + (size_t)s * NDIM;
    #pragma unroll
    for (int i = 0; i < 8; i++) {
      int k = i * 256 + t;
      float v = g0[(size_t)k * NDIM + col] * mvec[k] * rsc;
      dst[k] = f2bf(v);
    }
  }
}

// ---------------- K4: MFMA 16x16x32 bf16, split-K 4, atomic accumulate into C
__global__ __launch_bounds__(256) void k_mfma(const unsigned short* __restrict__ Aq,
                                              const unsigned short* __restrict__ Bt,
                                              float* __restrict__ C) {
  int t = threadIdx.x;
  int lane = t & 63;
  int wave = t >> 6;
  int m0 = blockIdx.y * 64 + (wave >> 1) * 32;
  int n0 = blockIdx.x * 64 + (wave & 1) * 32;
  int kc = blockIdx.z;
  int fr = lane & 15;            // A-row / B-col within 16-tile
  int kq = (lane >> 4) * 8;      // k-quad offset
  const unsigned short* Ap0 = Aq + (size_t)(m0 + fr) * NDIM + kc * 512 + kq;
  const unsigned short* Ap1 = Ap0 + (size_t)16 * NDIM;
  const unsigned short* Bp0 = Bt + (size_t)(n0 + fr) * NDIM + kc * 512 + kq;
  const unsigned short* Bp1 = Bp0 + (size_t)16 * NDIM;
  f32x4 acc00 = {0.f,0.f,0.f,0.f}, acc01 = acc00, acc10 = acc00, acc11 = acc00;
  #pragma unroll 4
  for (int i = 0; i < 16; i++) {
    int off = i * 32;
    bf16x8 a0 = *(const bf16x8*)(Ap0 + off);
    bf16x8 a1 = *(const bf16x8*)(Ap1 + off);
    bf16x8 b0 = *(const bf16x8*)(Bp0 + off);
    bf16x8 b1 = *(const bf16x8*)(Bp1 + off);
    acc00 = __builtin_amdgcn_mfma_f32_16x16x32_bf16(a0, b0, acc00, 0, 0, 0);
    acc01 = __builtin_amdgcn_mfma_f32_16x16x32_bf16(a0, b1, acc01, 0, 0, 0);
    acc10 = __builtin_amdgcn_mfma_f32_16x16x32_bf16(a1, b0, acc10, 0, 0, 0);
    acc11 = __builtin_amdgcn_mfma_f32_16x16x32_bf16(a1, b1, acc11, 0, 0, 0);
  }
  // C/D layout: col = lane&15, row = (lane>>4)*4 + reg   [m89-verified]
  int r0 = (lane >> 4) * 4;
  int c0 = lane & 15;
  #pragma unroll
  for (int r = 0; r < 4; r++) {
    atomicAdd(&C[(size_t)(m0 + r0 + r) * SDIM + n0 + c0],           acc00[r]);
    atomicAdd(&C[(size_t)(m0 + r0 + r) * SDIM + n0 + 16 + c0],      acc01[r]);
    atomicAdd(&C[(size_t)(m0 + 16 + r0 + r) * SDIM + n0 + c0],      acc10[r]);
    atomicAdd(&C[(size_t)(m0 + 16 + r0 + r) * SDIM + n0 + 16 + c0], acc11[r]);
  }
}

// ---------------- K5: global stats over C (diag mask on the fly, no write-back)
__global__ void k_stats(const float* __restrict__ C,
                        const int* __restrict__ qid, const int* __restrict__ sid,
                        double* __restrict__ stats) {
  __shared__ float r1[256], r2[256]; __shared__ int rc[256];
  int t = threadIdx.x;
  int idx4 = blockIdx.x * 256 + t;                 // float4 index, 512 blocks
  float4 v = ((const float4*)C)[idx4];
  int base = idx4 * 4;
  int q = base >> 9;
  int s0 = base & (SDIM - 1);
  int qv = qid[q];
  int4 sv = *(const int4*)(sid + s0);
  if (sv.x == qv) v.x = 0.f;
  if (sv.y == qv) v.y = 0.f;
  if (sv.z == qv) v.z = 0.f;
  if (sv.w == qv) v.w = 0.f;
  float s = 0.f, s2 = 0.f; int c = 0;
  float* vp = (float*)&v;
  #pragma unroll
  for (int p = 0; p < 4; p++) {
    float x = vp[p];
    if (x > 0.f) { s += x; s2 += x * x; c++; }
  }
  r1[t] = s; r2[t] = s2; rc[t] = c; __syncthreads();
  for (int st = 128; st > 0; st >>= 1) {
    if (t < st) { r1[t] += r1[t+st]; r2[t] += r2[t+st]; rc[t] += rc[t+st]; }
    __syncthreads();
  }
  if (t == 0) {
    atomicAdd(&stats[0], (double)r1[0]);
    atomicAdd(&stats[1], (double)r2[0]);
    atomicAdd(&stats[2], (double)rc[0]);
  }
}

// ---------------- K6: global calib + row-normalize (one block per query row)
__global__ void k_final(const float* __restrict__ C, const double* __restrict__ stats,
                        const int* __restrict__ qid, const int* __restrict__ sid,
                        const float* __restrict__ gw, const float* __restrict__ gb,
                        float* __restrict__ out) {
  __shared__ float red[256];
  int q = blockIdx.x, t = threadIdx.x;
  int qv = qid[q];
  double mean_d = stats[0] / stats[2];
  double var_d = stats[1] / stats[2] - mean_d * mean_d;
  float mean = (float)mean_d;
  float invstd = (float)(1.0 / sqrt(var_d));
  float w0 = gw[0], w1 = gw[1], w2 = gw[2], w3 = gw[3], w4 = gw[4], bb = gb[0];
  float vals[2]; float rs = 0.f;
  #pragma unroll
  for (int p = 0; p < 2; p++) {
    int s = t + p * 256;
    float x = C[(size_t)q * SDIM + s];
    if (sid[s] == qv) x = 0.f;   // diag mask on the fly
    float v = 0.f;
    if (x > 0.f) {
      float gn = (x - mean) * invstd;
      float m = fabsf(gn);
      float sgnsq = (m > 0.f) ? (gn / m) * sqrtf(m) : 0.f;  // sign(gn)*sqrt(|gn|)
      float acc = w0 * gn + w1 * sgnsq;
      float gm = gn * m; acc += w2 * gm;   // gn*|gn|
      gm *= m;           acc += w3 * gm;   // gn*|gn|^2
      gm *= m;           acc += w4 * gm;   // gn*|gn|^3
      acc += bb;
      v = (acc > 0.f ? acc : __expf(acc) - 1.f) + 1.f;  // elu + 1
    }
    vals[p] = v; rs += v;
  }
  red[t] = rs; __syncthreads();
  for (int st = 128; st > 0; st >>= 1) { if (t < st) red[t] += red[t+st]; __syncthreads(); }
  float tot = red[0];
  float inv = tot > 0.f ? 1.0f / tot : 0.f;   // divide_no_nan
  #pragma unroll
  for (int p = 0; p < 2; p++) {
    int s = t + p * 256;
    out[(size_t)q * SDIM + s] = vals[p] * inv;
  }
}

extern "C" void kernel_launch(void* const* d_in, const int* in_sizes, int n_in,
                              void* d_out, int out_size, void* d_ws, size_t ws_size,
                              hipStream_t stream) {
  const float* graph    = (const float*)d_in[0];
  const float* calib_w  = (const float*)d_in[1];
  const float* global_w = (const float*)d_in[2];
  const float* global_b = (const float*)d_in[3];
  const float* col_w    = (const float*)d_in[4];
  const int*   qid      = (const int*)d_in[5];
  const int*   sid      = (const int*)d_in[6];
  float* out = (float*)d_out;

  char* ws = (char*)d_ws;
  // Zero-region (single memset): colsum | stats | C
  float*  colsum = (float*)(ws + 0);              // 2048 f = 8 KiB
  double* stats  = (double*)(ws + 8192);          // 3 d
  float*  C      = (float*)(ws + 16384);          // Q*S f = 2 MiB
  // Non-zeroed scratch
  float*  rowsum = (float*)(ws + 2113536);        // 2048 f
  float*  leftv  = (float*)(ws + 2121728);
  float*  rightc = (float*)(ws + 2129920);
  float*  mvec   = (float*)(ws + 2138112);
  float*  g0     = (float*)(ws + 4194304);                       // N*N f = 16 MiB
  unsigned short* Aq = (unsigned short*)(ws + 20971520);         // Q*N bf16 = 4 MiB
  unsigned short* Bt = (unsigned short*)(ws + 25165824);         // S*N bf16 = 2 MiB

  hipMemsetAsync(ws, 0, 16384 + QDIM * SDIM * sizeof(float), stream);

  k_calib<<<NDIM / 4, 256, 0, stream>>>(graph, calib_w, g0, rowsum, colsum);
  k_factors<<<1, 1024, 0, stream>>>(rowsum, colsum, col_w, leftv, rightc, mvec);
  k_gather<<<QDIM + SDIM, 256, 0, stream>>>(g0, qid, sid, leftv, rightc, mvec, Aq, Bt);
  k_mfma<<<dim3(SDIM / 64, QDIM / 64, 4), 256, 0, stream>>>(Aq, Bt, C);
  k_stats<<<QDIM * SDIM / 1024, 256, 0, stream>>>(C, qid, sid, stats);
  k_final<<<QDIM, 256, 0, stream>>>(C, stats, qid, sid, global_w, global_b, out);
}

// Round 4
// 178.564 us; speedup vs baseline: 1.0244x; 1.0244x over previous
//
#include <hip/hip_runtime.h>
#include <hip/hip_bf16.h>

#define NDIM 2048
#define QDIM 1024
#define SDIM 512
#define NBINS 20

typedef __attribute__((ext_vector_type(8))) short bf16x8;
typedef __attribute__((ext_vector_type(4))) float f32x4;

__device__ __forceinline__ unsigned short f2bf(float f) {
  unsigned int u = __builtin_bit_cast(unsigned int, f);
  u += 0x7fffu + ((u >> 16) & 1u);   // RNE (no NaN in this data)
  return (unsigned short)(u >> 16);
}
__device__ __forceinline__ float bf2f(unsigned short h) {
  return __builtin_bit_cast(float, (unsigned int)h << 16);
}

// ---------------- K1: local calibration (1 row/block), 5-bin window, bf16 out, rowsum
__global__ __launch_bounds__(256) void k_calib(const float* __restrict__ graph,
                                               const float* __restrict__ calib_w,
                                               unsigned short* __restrict__ g0bf,
                                               float* __restrict__ rowsum) {
  __shared__ float sp[NBINS];
  __shared__ float red[256];
  int t = threadIdx.x;
  if (t == 0) {   // 20-bin softmax, recomputed per block (trivial)
    float m = -1e30f;
    for (int b = 0; b < NBINS; b++) m = fmaxf(m, calib_w[b]);
    float e[NBINS]; float s = 0.f;
    for (int b = 0; b < NBINS; b++) { e[b] = __expf(calib_w[b] - m); s += e[b]; }
    float inv = 1.0f / s;
    for (int b = 0; b < NBINS; b++) sp[b] = e[b] * inv;
  }
  __syncthreads();
  int row = blockIdx.x;
  const float4* src = (const float4*)(graph + (size_t)row * NDIM);
  float4 in0 = src[t * 2];
  float4 in1 = src[t * 2 + 1];
  float gv[8] = {in0.x, in0.y, in0.z, in0.w, in1.x, in1.y, in1.z, in1.w};
  unsigned short ov[8];
  float rs = 0.f;
  #pragma unroll
  for (int i = 0; i < 8; i++) {
    float g = gv[i];
    float v = 0.f;
    if (g > 0.f) {
      // only bins within 2 of b*=round(19g) matter: z<5e-11 beyond
      int bstar = (int)floorf(g * 19.0f + 0.5f);
      int lo = bstar - 2;
      lo = lo < 0 ? 0 : (lo > NBINS - 5 ? NBINS - 5 : lo);
      float num = 0.f, den = 0.f;
      #pragma unroll
      for (int w = 0; w < 5; w++) {
        int b = lo + w;
        float d = g - (float)b * (1.0f / 19.0f);
        float z = __expf(-950.0f * d * d);   // sig = (1/19)/50 = 1/950 all bins
        den += z; num += z * sp[b];
      }
      v = den > 0.f ? num / den : 0.f;
    }
    ov[i] = f2bf(v);
    rs += v;
  }
  uint4 packed;
  __builtin_memcpy(&packed, ov, 16);
  *(uint4*)(g0bf + (size_t)row * NDIM + t * 8) = packed;
  red[t] = rs; __syncthreads();
  for (int s = 128; s > 0; s >>= 1) { if (t < s) red[t] += red[t+s]; __syncthreads(); }
  if (t == 0) rowsum[row] = red[0];
}

// ---------------- K2: column sums of bf16 g0 (vectorized, atomic per 16-row strip)
__global__ __launch_bounds__(256) void k_colsum(const unsigned short* __restrict__ g0bf,
                                                float* __restrict__ colsum) {
  int t = threadIdx.x;
  int r0 = blockIdx.x * 16;           // 128 blocks
  int c0 = t * 8;
  float acc[8] = {0.f,0.f,0.f,0.f,0.f,0.f,0.f,0.f};
  for (int r = 0; r < 16; r++) {
    uint4 u = *(const uint4*)(g0bf + (size_t)(r0 + r) * NDIM + c0);
    unsigned short h[8];
    __builtin_memcpy(h, &u, 16);
    #pragma unroll
    for (int i = 0; i < 8; i++) acc[i] += bf2f(h[i]);
  }
  #pragma unroll
  for (int i = 0; i < 8; i++) atomicAdd(&colsum[c0 + i], acc[i]);
}

// ---------------- K3: factors (1 block, 1024t): col_w softmax + leftv/rightc/mvec
__global__ __launch_bounds__(1024) void k_factors(const float* __restrict__ rowsum,
                                                  const float* __restrict__ colsum,
                                                  const float* __restrict__ col_w,
                                                  float* __restrict__ leftv,
                                                  float* __restrict__ rightc,
                                                  float* __restrict__ mvec) {
  __shared__ float red[1024];
  int t = threadIdx.x;
  float a = col_w[t], b = col_w[t + 1024];
  red[t] = fmaxf(a, b); __syncthreads();
  for (int st = 512; st > 0; st >>= 1) { if (t < st) red[t] = fmaxf(red[t], red[t+st]); __syncthreads(); }
  float gmax = red[0]; __syncthreads();
  float ea = __expf(a - gmax), eb = __expf(b - gmax);
  red[t] = ea + eb; __syncthreads();
  for (int st = 512; st > 0; st >>= 1) { if (t < st) red[t] += red[t+st]; __syncthreads(); }
  float scale = (float)NDIM / red[0];
  #pragma unroll
  for (int h = 0; h < 2; h++) {
    int j = t + h * 1024;
    float cwj = (h == 0 ? ea : eb) * scale;
    float rsum = rowsum[j], csum = colsum[j];
    float l = rsum > 0.f ? 1.0f / sqrtf(rsum) : 0.f;   // divide_no_nan(1, sqrt(.))
    float rr = csum > 0.f ? 1.0f / sqrtf(csum) : 0.f;
    float rc = rr * cwj;
    leftv[j] = l;
    rightc[j] = rc;
    mvec[j] = l * rc;      // inner-k diagonal factor
  }
}

// ---------------- K4: Bt[s][k] = g0[k][sid[s]] * mvec[k]  (bf16; rightc deferred)
__global__ __launch_bounds__(256) void k_gatherBt(const unsigned short* __restrict__ g0bf,
                                                  const int* __restrict__ sid,
                                                  const float* __restrict__ mvec,
                                                  unsigned short* __restrict__ Bt) {
  int s = blockIdx.x, t = threadIdx.x;
  int col = sid[s];
  int k0 = t * 8;
  float4 m0_ = *(const float4*)(mvec + k0);
  float4 m1_ = *(const float4*)(mvec + k0 + 4);
  float mv[8] = {m0_.x, m0_.y, m0_.z, m0_.w, m1_.x, m1_.y, m1_.z, m1_.w};
  unsigned short ov[8];
  #pragma unroll
  for (int i = 0; i < 8; i++) {
    float g = bf2f(g0bf[(size_t)(k0 + i) * NDIM + col]);
    ov[i] = f2bf(g * mv[i]);
  }
  uint4 packed;
  __builtin_memcpy(&packed, ov, 16);
  *(uint4*)(Bt + (size_t)s * NDIM + k0) = packed;
}

// ---------------- K5: MFMA 16x16x32 bf16, A direct from g0 via qid, split-K 4 -> Cp
__global__ __launch_bounds__(256) void k_mfma(const unsigned short* __restrict__ g0bf,
                                              const unsigned short* __restrict__ Bt,
                                              const int* __restrict__ qid,
                                              float* __restrict__ Cp) {
  int t = threadIdx.x;
  int lane = t & 63;
  int wave = t >> 6;
  int m0 = blockIdx.y * 64 + (wave >> 1) * 32;
  int n0 = blockIdx.x * 64 + (wave & 1) * 32;
  int kc = blockIdx.z;
  int fr = lane & 15;            // A-row / B-col within 16-tile
  int kq = (lane >> 4) * 8;      // k-quad offset
  int qa0 = qid[m0 + fr];
  int qa1 = qid[m0 + 16 + fr];
  const unsigned short* Ap0 = g0bf + (size_t)qa0 * NDIM + kc * 512 + kq;
  const unsigned short* Ap1 = g0bf + (size_t)qa1 * NDIM + kc * 512 + kq;
  const unsigned short* Bp0 = Bt + (size_t)(n0 + fr) * NDIM + kc * 512 + kq;
  const unsigned short* Bp1 = Bp0 + (size_t)16 * NDIM;
  f32x4 acc00 = {0.f,0.f,0.f,0.f}, acc01 = acc00, acc10 = acc00, acc11 = acc00;
  #pragma unroll 4
  for (int i = 0; i < 16; i++) {
    int off = i * 32;
    bf16x8 a0 = *(const bf16x8*)(Ap0 + off);
    bf16x8 a1 = *(const bf16x8*)(Ap1 + off);
    bf16x8 b0 = *(const bf16x8*)(Bp0 + off);
    bf16x8 b1 = *(const bf16x8*)(Bp1 + off);
    acc00 = __builtin_amdgcn_mfma_f32_16x16x32_bf16(a0, b0, acc00, 0, 0, 0);
    acc01 = __builtin_amdgcn_mfma_f32_16x16x32_bf16(a0, b1, acc01, 0, 0, 0);
    acc10 = __builtin_amdgcn_mfma_f32_16x16x32_bf16(a1, b0, acc10, 0, 0, 0);
    acc11 = __builtin_amdgcn_mfma_f32_16x16x32_bf16(a1, b1, acc11, 0, 0, 0);
  }
  // C/D layout: col = lane&15, row = (lane>>4)*4 + reg   [m89-verified]
  float* Cb = Cp + ((size_t)kc << 19);   // kc * QDIM * SDIM
  int r0 = (lane >> 4) * 4;
  int c0 = lane & 15;
  #pragma unroll
  for (int r = 0; r < 4; r++) {
    Cb[(size_t)(m0 + r0 + r) * SDIM + n0 + c0]           = acc00[r];
    Cb[(size_t)(m0 + r0 + r) * SDIM + n0 + 16 + c0]      = acc01[r];
    Cb[(size_t)(m0 + 16 + r0 + r) * SDIM + n0 + c0]      = acc10[r];
    Cb[(size_t)(m0 + 16 + r0 + r) * SDIM + n0 + 16 + c0] = acc11[r];
  }
}

// ---------------- K6: reduce partials, apply leftv/rightc (fp32), diag mask, C + stats
__global__ void k_reduce_stats(const float* __restrict__ Cp,
                               const int* __restrict__ qid, const int* __restrict__ sid,
                               const float* __restrict__ leftv, const float* __restrict__ rightc,
                               float* __restrict__ C, double* __restrict__ stats) {
  __shared__ float r1[256], r2[256]; __shared__ int rc[256];
  int t = threadIdx.x;
  int idx4 = blockIdx.x * 256 + t;                 // float4 index, 512 blocks
  const float4* Cp4 = (const float4*)Cp;
  const int STRIDE4 = QDIM * SDIM / 4;             // 131072
  float4 v = Cp4[idx4];
  float4 v1 = Cp4[idx4 + STRIDE4];
  float4 v2 = Cp4[idx4 + 2 * STRIDE4];
  float4 v3 = Cp4[idx4 + 3 * STRIDE4];
  v.x += v1.x + v2.x + v3.x; v.y += v1.y + v2.y + v3.y;
  v.z += v1.z + v2.z + v3.z; v.w += v1.w + v2.w + v3.w;
  int base = idx4 * 4;
  int q = base >> 9;
  int s0 = base & (SDIM - 1);
  int qv = qid[q];
  float lq = leftv[qv];
  int4 sv = *(const int4*)(sid + s0);
  v.x *= lq * rightc[sv.x];
  v.y *= lq * rightc[sv.y];
  v.z *= lq * rightc[sv.z];
  v.w *= lq * rightc[sv.w];
  if (sv.x == qv) v.x = 0.f;
  if (sv.y == qv) v.y = 0.f;
  if (sv.z == qv) v.z = 0.f;
  if (sv.w == qv) v.w = 0.f;
  ((float4*)C)[idx4] = v;
  float s = 0.f, s2 = 0.f; int c = 0;
  float* vp = (float*)&v;
  #pragma unroll
  for (int p = 0; p < 4; p++) {
    float x = vp[p];
    if (x > 0.f) { s += x; s2 += x * x; c++; }
  }
  r1[t] = s; r2[t] = s2; rc[t] = c; __syncthreads();
  for (int st = 128; st > 0; st >>= 1) {
    if (t < st) { r1[t] += r1[t+st]; r2[t] += r2[t+st]; rc[t] += rc[t+st]; }
    __syncthreads();
  }
  if (t == 0) {
    atomicAdd(&stats[0], (double)r1[0]);
    atomicAdd(&stats[1], (double)r2[0]);
    atomicAdd(&stats[2], (double)rc[0]);
  }
}

// ---------------- K7: global calib + row-normalize (one block per query row)
__global__ void k_final(const float* __restrict__ C, const double* __restrict__ stats,
                        const float* __restrict__ gw, const float* __restrict__ gb,
                        float* __restrict__ out) {
  __shared__ float red[256];
  int q = blockIdx.x, t = threadIdx.x;
  double mean_d = stats[0] / stats[2];
  double var_d = stats[1] / stats[2] - mean_d * mean_d;
  float mean = (float)mean_d;
  float invstd = (float)(1.0 / sqrt(var_d));
  float w0 = gw[0], w1 = gw[1], w2 = gw[2], w3 = gw[3], w4 = gw[4], bb = gb[0];
  float vals[2]; float rs = 0.f;
  #pragma unroll
  for (int p = 0; p < 2; p++) {
    int s = t + p * 256;
    float x = C[(size_t)q * SDIM + s];
    float v = 0.f;
    if (x > 0.f) {
      float gn = (x - mean) * invstd;
      float m = fabsf(gn);
      float sgnsq = (m > 0.f) ? (gn / m) * sqrtf(m) : 0.f;  // sign(gn)*sqrt(|gn|)
      float acc = w0 * gn + w1 * sgnsq;
      float gm = gn * m; acc += w2 * gm;   // gn*|gn|
      gm *= m;           acc += w3 * gm;   // gn*|gn|^2
      gm *= m;           acc += w4 * gm;   // gn*|gn|^3
      acc += bb;
      v = (acc > 0.f ? acc : __expf(acc) - 1.f) + 1.f;  // elu + 1
    }
    vals[p] = v; rs += v;
  }
  red[t] = rs; __syncthreads();
  for (int st = 128; st > 0; st >>= 1) { if (t < st) red[t] += red[t+st]; __syncthreads(); }
  float tot = red[0];
  float inv = tot > 0.f ? 1.0f / tot : 0.f;   // divide_no_nan
  #pragma unroll
  for (int p = 0; p < 2; p++) {
    int s = t + p * 256;
    out[(size_t)q * SDIM + s] = vals[p] * inv;
  }
}

extern "C" void kernel_launch(void* const* d_in, const int* in_sizes, int n_in,
                              void* d_out, int out_size, void* d_ws, size_t ws_size,
                              hipStream_t stream) {
  const float* graph    = (const float*)d_in[0];
  const float* calib_w  = (const float*)d_in[1];
  const float* global_w = (const float*)d_in[2];
  const float* global_b = (const float*)d_in[3];
  const float* col_w    = (const float*)d_in[4];
  const int*   qid      = (const int*)d_in[5];
  const int*   sid      = (const int*)d_in[6];
  float* out = (float*)d_out;

  char* ws = (char*)d_ws;
  // zero-region (one tiny memset): colsum | stats
  float*  colsum = (float*)(ws + 0);                 // 2048 f = 8 KiB
  double* stats  = (double*)(ws + 8192);             // 3 d
  float*  rowsum = (float*)(ws + 16384);             // 2048 f
  float*  leftv  = (float*)(ws + 24576);
  float*  rightc = (float*)(ws + 32768);
  float*  mvec   = (float*)(ws + 40960);
  unsigned short* g0bf = (unsigned short*)(ws + 65536);          // N*N bf16 = 8 MiB
  unsigned short* Bt   = (unsigned short*)(ws + 65536 + 8388608);        // S*N bf16 = 2 MiB
  float*  Cp     = (float*)(ws + 65536 + 8388608 + 2097152);             // 4*Q*S f = 8 MiB
  float*  C      = (float*)(ws + 65536 + 8388608 + 2097152 + 8388608);   // Q*S f = 2 MiB

  hipMemsetAsync(ws, 0, 16384, stream);

  k_calib<<<NDIM, 256, 0, stream>>>(graph, calib_w, g0bf, rowsum);
  k_colsum<<<NDIM / 16, 256, 0, stream>>>(g0bf, colsum);
  k_factors<<<1, 1024, 0, stream>>>(rowsum, colsum, col_w, leftv, rightc, mvec);
  k_gatherBt<<<SDIM, 256, 0, stream>>>(g0bf, sid, mvec, Bt);
  k_mfma<<<dim3(SDIM / 64, QDIM / 64, 4), 256, 0, stream>>>(g0bf, Bt, qid, Cp);
  k_reduce_stats<<<QDIM * SDIM / 1024, 256, 0, stream>>>(Cp, qid, sid, leftv, rightc, C, stats);
  k_final<<<QDIM, 256, 0, stream>>>(C, stats, global_w, global_b, out);
}